// Round 5
// baseline (4299.098 us; speedup 1.0000x reference)
//
#include <hip/hip_runtime.h>
#include <hip/hip_cooperative_groups.h>
#include <hip/hip_bf16.h>
#include <hip/hip_fp16.h>
#include <math.h>

// DAGNN propagation, CSR-gather, fp16 state.
// Round 18: revert perm (r16/r17 falsified). Persistent cooperative multi-hop
// kernel: 1536 blocks x 256 thr, each block owns ~66 nodes; cols staged in LDS
// ONCE, per-tile metadata (beg/deg/norm/maxdeg) in registers ONCE, all 10 hops
// run in-kernel with grid.sync() between hops (init folded in). Gather = r14
// G8 geometry (8 lanes/node, 16B loads, clamped unconditional rounds). Col
// broadcast = 1 LDS read (8 lanes same addr) instead of shuffles.
// Host falls back to r14 per-hop launches if cooperative launch fails.

namespace cg = cooperative_groups;

#define DIM 64
#define BSH 9
#define BSZ 512                 // nodes per bucket
#define MAXNB 256               // buckets must fit one 256-thread scan block
#define A2_CHUNK 4096           // edges per A2 block
#define GRID_C 1536             // cooperative grid (6 blocks/CU x 256 CU)
#define CAPE 2048               // LDS col cache capacity (ints)
#define MAXTILES 4              // up to 128 nodes/block

// ---- zero int region ----
__global__ void zero_int_kernel(int* __restrict__ p, int n) {
    int i = blockIdx.x * blockDim.x + threadIdx.x;
    if (i < n) p[i] = 0;
}

// ---- A1: bucket histogram via LDS bins ----
__global__ void bin_count_kernel(const int* __restrict__ dst,
                                 int* __restrict__ binCount, int E) {
    __shared__ int lb[MAXNB];
    if (threadIdx.x < MAXNB) lb[threadIdx.x] = 0;
    __syncthreads();
    for (int e = blockIdx.x * blockDim.x + threadIdx.x; e < E;
         e += gridDim.x * blockDim.x) {
        atomicAdd(&lb[dst[e] >> BSH], 1);
    }
    __syncthreads();
    if (threadIdx.x < MAXNB && lb[threadIdx.x])
        atomicAdd(&binCount[threadIdx.x], lb[threadIdx.x]);
}

// ---- S: exclusive scan of bucket counts; init tails; rp[N]=E ----
__global__ void binscan_kernel(const int* __restrict__ binCount,
                               int* __restrict__ binBase, int* __restrict__ tail,
                               int* __restrict__ rp, int NB, int N, int E) {
    __shared__ int lds[256];
    int t = threadIdx.x;
    int v = (t < NB) ? binCount[t] : 0;
    lds[t] = v;
    __syncthreads();
    for (int off = 1; off < 256; off <<= 1) {
        int x = (t >= off) ? lds[t - off] : 0;
        __syncthreads();
        lds[t] += x;
        __syncthreads();
    }
    int excl = lds[t] - v;
    if (t < NB) { binBase[t] = excl; tail[t] = excl; }
    if (t == 0) { binBase[NB] = E; rp[N] = E; }
}

// ---- A2: LDS-binned scatter of (src,dst) pairs into bucket regions ----
__global__ void bin_scatter_kernel(const int* __restrict__ src,
                                   const int* __restrict__ dst,
                                   int* __restrict__ tail,
                                   int2* __restrict__ pairs, int E) {
    __shared__ int cnt[MAXNB];
    __shared__ int base[MAXNB];
    int t = threadIdx.x;
    int begE = blockIdx.x * A2_CHUNK;
    int endE = begE + A2_CHUNK; if (endE > E) endE = E;
    if (t < MAXNB) cnt[t] = 0;
    __syncthreads();
    for (int e = begE + t; e < endE; e += blockDim.x)
        atomicAdd(&cnt[dst[e] >> BSH], 1);
    __syncthreads();
    if (t < MAXNB) {
        int c = cnt[t];
        base[t] = c ? atomicAdd(&tail[t], c) : 0;   // one global atomic / bucket / block
        cnt[t] = 0;                                  // reuse as local cursor
    }
    __syncthreads();
    for (int e = begE + t; e < endE; e += blockDim.x) {
        int d = dst[e];
        int b = d >> BSH;
        int pos = base[b] + atomicAdd(&cnt[b], 1);
        pairs[pos] = make_int2(src[e], d);           // coalesced-ish: ~168B windows
    }
}

// ---- B: per-bucket CSR finalize: degree -> scan -> rp/norm/col ----
__global__ void bucket_build_kernel(const int2* __restrict__ pairs,
                                    const int* __restrict__ binBase,
                                    int* __restrict__ col, int* __restrict__ rp,
                                    float* __restrict__ norm, int N) {
    __shared__ int degL[BSZ];
    __shared__ int off[BSZ];
    __shared__ int tmp[256];
    int b  = blockIdx.x;
    int lo = b << BSH;
    int cnt = N - lo; if (cnt > BSZ) cnt = BSZ;
    int t = threadIdx.x;
    degL[t] = 0; degL[t + 256] = 0;
    __syncthreads();
    int rbeg = binBase[b], rend = binBase[b + 1];
    for (int j = rbeg + t; j < rend; j += 256)
        atomicAdd(&degL[pairs[j].y - lo], 1);
    __syncthreads();
    int d0 = degL[2 * t], d1 = degL[2 * t + 1];
    int s2 = d0 + d1;
    tmp[t] = s2;
    __syncthreads();
    for (int o = 1; o < 256; o <<= 1) {
        int x = (t >= o) ? tmp[t - o] : 0;
        __syncthreads();
        tmp[t] += x;
        __syncthreads();
    }
    int e2 = tmp[t] - s2;                  // local exclusive offset
    off[2 * t]     = e2;
    off[2 * t + 1] = e2 + d0;
    __syncthreads();
    if (2 * t < cnt) {
        rp[lo + 2 * t] = rbeg + e2;
        norm[lo + 2 * t] = rsqrtf((float)d0);
    }
    if (2 * t + 1 < cnt) {
        rp[lo + 2 * t + 1] = rbeg + e2 + d0;
        norm[lo + 2 * t + 1] = rsqrtf((float)d1);
    }
    for (int j = rbeg + t; j < rend; j += 256) {
        int2 p = pairs[j];
        int slot = atomicAdd(&off[p.y - lo], 1);     // local cursor
        col[rbeg + slot] = p.x;                      // L2-hot 27KB window
    }
}

// ---- persistent cooperative multi-hop kernel ----
#define HOP_TILE_BODY(COLREAD)                                                 \
    for (int r = 0; r < rounds; ++r) {                                         \
        int rb = r << 3;                                                       \
        _Pragma("unroll")                                                      \
        for (int jj = 0; jj < 8; ++jj) {                                       \
            int ee = rb + jj;                                                  \
            int ic = min(ee, deg - 1); ic = max(ic, 0);                        \
            int cc = (COLREAD);                                                \
            float4 raw = *(const float4*)(wsub + ((size_t)cc << 6));           \
            if (ee < deg) {                                                    \
                const __half2* h2 = (const __half2*)&raw;                      \
                float2 f0 = __half22float2(h2[0]);                             \
                float2 f1 = __half22float2(h2[1]);                             \
                float2 f2 = __half22float2(h2[2]);                             \
                float2 f3 = __half22float2(h2[3]);                             \
                acc[0] += f0.x; acc[1] += f0.y;                                \
                acc[2] += f1.x; acc[3] += f1.y;                                \
                acc[4] += f2.x; acc[5] += f2.y;                                \
                acc[6] += f3.x; acc[7] += f3.y;                                \
            }                                                                  \
        }                                                                      \
    }

__global__ __launch_bounds__(256, 6)
void multi_hop_kernel(const float* __restrict__ feats,
                      const float* __restrict__ norm,
                      const int* __restrict__ rp,
                      const int* __restrict__ col,
                      __half* __restrict__ wbase,
                      int N, int nper, int K) {
    cg::grid_group gridg = cg::this_grid();
    __shared__ int lcol[CAPE];

    const int n0   = blockIdx.x * nper;
    const int nEnd = min(N, n0 + nper);
    const bool active = (n0 < N);
    const int lane = threadIdx.x & 63;
    const int wv   = threadIdx.x >> 6;
    const int g    = lane >> 3;
    const int sub  = lane & 7;
    const size_t SE = (size_t)N << 6;

    int eBase = 0, cnt = 0;
    if (active) {
        eBase = rp[n0];
        cnt = rp[nEnd] - eBase;
        if (cnt <= CAPE)
            for (int e = threadIdx.x; e < cnt; e += 256)
                lcol[e] = col[eBase + e];
    }
    const bool okL = active && (cnt <= CAPE);

    // hop-invariant per-tile metadata in registers (static-indexed arrays)
    int   nT[MAXTILES], begL[MAXTILES], degT[MAXTILES], mdT[MAXTILES];
    float nmT[MAXTILES];
    bool  vT[MAXTILES];
    #pragma unroll
    for (int t = 0; t < MAXTILES; ++t) {
        int n = n0 + (t << 5) + (wv << 3) + g;
        bool valid = active && (n < nEnd);
        int nc = valid ? n : (active ? nEnd - 1 : 0);
        int bg = active ? rp[nc] : 0;
        int dg = valid ? (rp[nc + 1] - bg) : 0;
        float nm = valid ? norm[nc] : 0.0f;
        nT[t] = n; begL[t] = bg - eBase; degT[t] = dg; nmT[t] = nm; vT[t] = valid;
        int md = dg;
        md = max(md, __shfl_xor(md, 8, 64));
        md = max(md, __shfl_xor(md, 16, 64));
        md = max(md, __shfl_xor(md, 32, 64));
        mdT[t] = md;
    }
    __syncthreads();            // lcol filled before gathers

    // init: w0 = half(feats * norm)
    if (active) {
        #pragma unroll
        for (int t = 0; t < MAXTILES; ++t) {
            if (vT[t]) {
                size_t base = ((size_t)nT[t] << 6) + (sub << 3);
                float4 f0 = *(const float4*)(feats + base);
                float4 f1 = *(const float4*)(feats + base + 4);
                float nm = nmT[t];
                __half2 hv[4];
                hv[0] = __floats2half2_rn(f0.x * nm, f0.y * nm);
                hv[1] = __floats2half2_rn(f0.z * nm, f0.w * nm);
                hv[2] = __floats2half2_rn(f1.x * nm, f1.y * nm);
                hv[3] = __floats2half2_rn(f1.z * nm, f1.w * nm);
                *(float4*)(wbase + base) = *(const float4*)hv;
            }
        }
    }
    __threadfence();
    gridg.sync();

    const __half* cur = wbase;
    __half* nxt = wbase + SE;
    for (int k = 0; k < K; ++k) {
        if (active) {
            #pragma unroll
            for (int t = 0; t < MAXTILES; ++t) {
                int md = mdT[t];
                if (md > 0) {
                    float acc[8];
                    #pragma unroll
                    for (int i = 0; i < 8; ++i) acc[i] = 0.0f;
                    const __half* wsub = cur + (sub << 3);
                    int deg = degT[t];
                    int bL  = begL[t];
                    int rounds = (md + 7) >> 3;
                    if (okL) {
                        HOP_TILE_BODY(lcol[bL + ic])
                    } else {
                        HOP_TILE_BODY(col[eBase + bL + ic])
                    }
                    if (vT[t]) {
                        float n2 = nmT[t] * nmT[t];
                        __half2 hv[4];
                        hv[0] = __floats2half2_rn(acc[0] * n2, acc[1] * n2);
                        hv[1] = __floats2half2_rn(acc[2] * n2, acc[3] * n2);
                        hv[2] = __floats2half2_rn(acc[4] * n2, acc[5] * n2);
                        hv[3] = __floats2half2_rn(acc[6] * n2, acc[7] * n2);
                        *(float4*)(nxt + ((size_t)nT[t] << 6) + (sub << 3)) =
                            *(const float4*)hv;
                    }
                }
            }
        }
        __threadfence();
        gridg.sync();
        cur = nxt; nxt += SE;
    }
}

// ---- init (fallback full path): w0 = half(feats*norm), node-major ----
__global__ void init_w0_kernel(const float* __restrict__ feats,
                               const float* __restrict__ norm,
                               __half* __restrict__ w, int N) {
    int n = blockIdx.x * (blockDim.x >> 6) + (threadIdx.x >> 6);
    int lane = threadIdx.x & 63;
    if (n >= N) return;
    size_t idx = ((size_t)n << 6) + lane;
    w[idx] = __float2half(feats[idx] * norm[n]);
}

// ---- hop (r14 G8, fallback): 8 lanes/node, 8 nodes/wave ----
__global__ void gather_hop_store_kernel(const __half* __restrict__ w,
                                        const int* __restrict__ rp,
                                        const int* __restrict__ col,
                                        const float* __restrict__ norm,
                                        __half* __restrict__ wnext, int N) {
    int wid  = (blockIdx.x * blockDim.x + threadIdx.x) >> 6;
    int lane = threadIdx.x & 63;
    int g    = lane >> 3;
    int sub  = lane & 7;
    int gbase = lane & 56;
    int n    = (wid << 3) + g;
    bool valid = (n < N);
    int nc = valid ? n : (N - 1);

    int beg = rp[nc];
    int end = rp[nc + 1];
    int deg = valid ? (end - beg) : 0;
    float nm = norm[nc];

    int maxdeg = deg;
    maxdeg = max(maxdeg, __shfl_xor(maxdeg, 8, 64));
    maxdeg = max(maxdeg, __shfl_xor(maxdeg, 16, 64));
    maxdeg = max(maxdeg, __shfl_xor(maxdeg, 32, 64));

    float acc[8];
    #pragma unroll
    for (int i = 0; i < 8; ++i) acc[i] = 0.0f;

    const __half* wsub = w + (sub << 3);

    for (int base = 0; base < maxdeg; base += 8) {
        int i0 = beg + base + sub;
        int c0 = (i0 < end) ? col[i0] : 0;
        #pragma unroll
        for (int jj = 0; jj < 8; jj += 2) {
            if (base + jj >= maxdeg) break;
            int ccA = __shfl(c0, gbase + jj, 64);
            int ccB = __shfl(c0, gbase + jj + 1, 64);
            float4 rA = *(const float4*)(wsub + ((size_t)ccA << 6));
            float4 rB = *(const float4*)(wsub + ((size_t)ccB << 6));
            if (base + jj < deg) {
                const __half2* h2 = (const __half2*)&rA;
                float2 f0 = __half22float2(h2[0]);
                float2 f1 = __half22float2(h2[1]);
                float2 f2 = __half22float2(h2[2]);
                float2 f3 = __half22float2(h2[3]);
                acc[0] += f0.x; acc[1] += f0.y;
                acc[2] += f1.x; acc[3] += f1.y;
                acc[4] += f2.x; acc[5] += f2.y;
                acc[6] += f3.x; acc[7] += f3.y;
            }
            if (base + jj + 1 < deg) {
                const __half2* h2 = (const __half2*)&rB;
                float2 f0 = __half22float2(h2[0]);
                float2 f1 = __half22float2(h2[1]);
                float2 f2 = __half22float2(h2[2]);
                float2 f3 = __half22float2(h2[3]);
                acc[0] += f0.x; acc[1] += f0.y;
                acc[2] += f1.x; acc[3] += f1.y;
                acc[4] += f2.x; acc[5] += f2.y;
                acc[6] += f3.x; acc[7] += f3.y;
            }
        }
    }

    if (valid) {
        float n2 = nm * nm;
        __half2 hv[4];
        hv[0] = __floats2half2_rn(acc[0] * n2, acc[1] * n2);
        hv[1] = __floats2half2_rn(acc[2] * n2, acc[3] * n2);
        hv[2] = __floats2half2_rn(acc[4] * n2, acc[5] * n2);
        hv[3] = __floats2half2_rn(acc[6] * n2, acc[7] * n2);
        *(float4*)(wnext + ((size_t)n << 6) + (sub << 3)) = *(const float4*)hv;
    }
}

// ---- readout (G8): 8 lanes/node; 3-op intra-group dot reduce ----
__global__ void readout_kernel(const __half* __restrict__ wbase,
                               const float* __restrict__ norm,
                               const float* __restrict__ s,
                               float* __restrict__ out,
                               int N, int nk, size_t kstride) {
    int wid  = (blockIdx.x * blockDim.x + threadIdx.x) >> 6;
    int lane = threadIdx.x & 63;
    int g    = lane >> 3;
    int sub  = lane & 7;
    int n    = (wid << 3) + g;
    bool valid = (n < N);
    int nc = valid ? n : (N - 1);

    float4 sa = *(const float4*)(s + (sub << 3));
    float4 sb = *(const float4*)(s + (sub << 3) + 4);

    float inm = 1.0f / norm[nc];
    size_t rowoff = ((size_t)nc << 6) + (sub << 3);

    float acc[8];
    #pragma unroll
    for (int i = 0; i < 8; ++i) acc[i] = 0.0f;

    for (int k = 0; k < nk; ++k) {
        float4 raw = *(const float4*)(wbase + rowoff + (size_t)k * kstride);
        const __half2* h2 = (const __half2*)&raw;
        float2 f0 = __half22float2(h2[0]);
        float2 f1 = __half22float2(h2[1]);
        float2 f2 = __half22float2(h2[2]);
        float2 f3 = __half22float2(h2[3]);
        float p = f0.x * sa.x + f0.y * sa.y + f1.x * sa.z + f1.y * sa.w
                + f2.x * sb.x + f2.y * sb.y + f3.x * sb.z + f3.y * sb.w;
        p += __shfl_xor(p, 1, 64);
        p += __shfl_xor(p, 2, 64);
        p += __shfl_xor(p, 4, 64);
        float gate = 1.0f / (1.0f + expf(-p * inm));
        float g2 = gate * inm;
        acc[0] += g2 * f0.x; acc[1] += g2 * f0.y;
        acc[2] += g2 * f1.x; acc[3] += g2 * f1.y;
        acc[4] += g2 * f2.x; acc[5] += g2 * f2.y;
        acc[6] += g2 * f3.x; acc[7] += g2 * f3.y;
    }

    if (valid) {
        float4 o0 = make_float4(acc[0], acc[1], acc[2], acc[3]);
        float4 o1 = make_float4(acc[4], acc[5], acc[6], acc[7]);
        float4* o = (float4*)(out + rowoff);
        o[0] = o0; o[1] = o1;
    }
}

// ---- fallback (small ws): fused hop with out RMW ----
__global__ void init_kernel(const float* __restrict__ feats,
                            const float* __restrict__ norm,
                            const float* __restrict__ s,
                            float* __restrict__ out,
                            __half* __restrict__ w, int N) {
    int n = blockIdx.x * (blockDim.x >> 6) + (threadIdx.x >> 6);
    int lane = threadIdx.x & 63;
    if (n >= N) return;
    size_t idx = ((size_t)n << 6) + lane;
    float v = feats[idx];
    float p = v * s[lane];
    #pragma unroll
    for (int off = 32; off; off >>= 1) p += __shfl_xor(p, off, 64);
    float gate = 1.0f / (1.0f + expf(-p));
    out[idx] = gate * v;
    w[idx] = __float2half(v * norm[n]);
}

__global__ void gather_hop_kernel(const __half* __restrict__ w,
                                  const int* __restrict__ rp,
                                  const int* __restrict__ col,
                                  const float* __restrict__ norm,
                                  const float* __restrict__ s,
                                  float* __restrict__ out,
                                  __half* __restrict__ wnext,
                                  int N, int write_next) {
    int n = blockIdx.x * (blockDim.x >> 6) + (threadIdx.x >> 6);
    if (n >= N) return;
    int lane = threadIdx.x & 63;
    int e_sub = lane >> 3;
    int c     = lane & 7;

    int beg = rp[n];
    int end = rp[n + 1];

    float acc[8];
    #pragma unroll
    for (int i = 0; i < 8; ++i) acc[i] = 0.0f;

    for (int j = beg + e_sub; j < end; j += 8) {
        int cc = col[j];
        float4 raw = *(const float4*)(w + ((size_t)cc << 6) + (c << 3));
        const __half2* h2 = (const __half2*)&raw;
        float2 f0 = __half22float2(h2[0]);
        float2 f1 = __half22float2(h2[1]);
        float2 f2 = __half22float2(h2[2]);
        float2 f3 = __half22float2(h2[3]);
        acc[0] += f0.x; acc[1] += f0.y;
        acc[2] += f1.x; acc[3] += f1.y;
        acc[4] += f2.x; acc[5] += f2.y;
        acc[6] += f3.x; acc[7] += f3.y;
    }

    #pragma unroll
    for (int off = 8; off < 64; off <<= 1) {
        #pragma unroll
        for (int i = 0; i < 8; ++i) acc[i] += __shfl_xor(acc[i], off, 64);
    }

    float nm = norm[n];
    float v[8];
    #pragma unroll
    for (int i = 0; i < 8; ++i) v[i] = acc[i] * nm;

    float4 sa = *(const float4*)(s + (c << 3));
    float4 sb = *(const float4*)(s + (c << 3) + 4);
    float p = v[0] * sa.x + v[1] * sa.y + v[2] * sa.z + v[3] * sa.w
            + v[4] * sb.x + v[5] * sb.y + v[6] * sb.z + v[7] * sb.w;
    #pragma unroll
    for (int off = 1; off < 8; off <<= 1) p += __shfl_xor(p, off, 64);
    float gate = 1.0f / (1.0f + expf(-p));

    size_t base = ((size_t)n << 6) + (c << 3);
    if (e_sub == 0) {
        float4* o = (float4*)(out + base);
        float4 o0 = o[0], o1 = o[1];
        o0.x += gate * v[0]; o0.y += gate * v[1];
        o0.z += gate * v[2]; o0.w += gate * v[3];
        o1.x += gate * v[4]; o1.y += gate * v[5];
        o1.z += gate * v[6]; o1.w += gate * v[7];
        o[0] = o0; o[1] = o1;
    } else if (e_sub == 1 && write_next) {
        __half2 hv[4];
        hv[0] = __floats2half2_rn(v[0] * nm, v[1] * nm);
        hv[1] = __floats2half2_rn(v[2] * nm, v[3] * nm);
        hv[2] = __floats2half2_rn(v[4] * nm, v[5] * nm);
        hv[3] = __floats2half2_rn(v[6] * nm, v[7] * nm);
        *(float4*)(wnext + base) = *(const float4*)hv;
    }
}

extern "C" void kernel_launch(void* const* d_in, const int* in_sizes, int n_in,
                              void* d_out, int out_size, void* d_ws, size_t ws_size,
                              hipStream_t stream) {
    const float* feats = (const float*)d_in[0];
    const float* s     = (const float*)d_in[1];
    const int*   src   = (const int*)d_in[2];
    const int*   dst   = (const int*)d_in[3];
    float* out = (float*)d_out;

    const int N = in_sizes[0] / DIM;
    const int E = in_sizes[2];
    const int K = 10;
    const int NB = (N + BSZ - 1) >> BSH;    // 196 for N=100000; must be <= 256

    const int BLK = 256;
    const int wavesPerBlk = BLK / 64;
    int nodeBlocks  = (N + wavesPerBlk - 1) / wavesPerBlk;
    int nodeBlocks8 = (N + wavesPerBlk * 8 - 1) / (wavesPerBlk * 8);
    int a2Blocks = (E + A2_CHUNK - 1) / A2_CHUNK;

    size_t stateElems = (size_t)N * DIM;
    size_t intCount = (size_t)(N + 1) + E + 256 + 257 + 256;
    size_t need_full = (size_t)N * 4 + (size_t)(K + 1) * stateElems * 2
                     + intCount * 4 + (size_t)E * 8 + 64;
    int full = (ws_size >= need_full) ? 1 : 0;
    int nbuf = full ? (K + 1) : 2;

    float*  norm    = (float*)d_ws;
    __half* wbase   = (__half*)(norm + N);
    int*    rp      = (int*)(wbase + (size_t)nbuf * stateElems);
    int*    col     = rp + (N + 1);
    int*    binCount= col + E;
    int*    binBase = binCount + 256;
    int*    tail    = binBase + 257;
    size_t  poff    = (size_t)((char*)(tail + 256) - (char*)d_ws);
    poff = (poff + 7) & ~(size_t)7;
    int2*   pairs   = (int2*)((char*)d_ws + poff);

    // ---- build: histogram -> scan -> binned scatter -> bucket finalize ----
    zero_int_kernel<<<1, 256, 0, stream>>>(binCount, 256);
    bin_count_kernel<<<512, BLK, 0, stream>>>(dst, binCount, E);
    binscan_kernel<<<1, 256, 0, stream>>>(binCount, binBase, tail, rp, NB, N, E);
    bin_scatter_kernel<<<a2Blocks, BLK, 0, stream>>>(src, dst, tail, pairs, E);
    bucket_build_kernel<<<NB, 256, 0, stream>>>(pairs, binBase, col, rp, norm, N);

    if (full) {
        int nper = (N + GRID_C - 1) / GRID_C;
        bool coop_ok = false;
        if (nper <= 32 * MAXTILES) {
            int Nv = N, nperv = nper, Kv = K;
            void* args[] = {(void*)&feats, (void*)&norm, (void*)&rp, (void*)&col,
                            (void*)&wbase, (void*)&Nv, (void*)&nperv, (void*)&Kv};
            hipError_t err = hipLaunchCooperativeKernel(
                (const void*)multi_hop_kernel, dim3(GRID_C), dim3(BLK),
                args, 0, stream);
            coop_ok = (err == hipSuccess);
        }
        if (!coop_ok) {
            // fallback: r14 per-hop launches
            init_w0_kernel<<<nodeBlocks, BLK, 0, stream>>>(feats, norm, wbase, N);
            for (int k = 0; k < K; ++k) {
                const __half* cur = wbase + (size_t)k * stateElems;
                __half* nxt = wbase + (size_t)(k + 1) * stateElems;
                gather_hop_store_kernel<<<nodeBlocks8, BLK, 0, stream>>>(cur, rp,
                                                                         col, norm,
                                                                         nxt, N);
            }
        }
        readout_kernel<<<nodeBlocks8, BLK, 0, stream>>>(wbase, norm, s, out,
                                                        N, K + 1, stateElems);
    } else {
        __half* wA = wbase;
        __half* wB = wbase + stateElems;
        init_kernel<<<nodeBlocks, BLK, 0, stream>>>(feats, norm, s, out, wA, N);
        __half* cur = wA;
        __half* nxt = wB;
        for (int k = 0; k < K; ++k) {
            int write_next = (k < K - 1) ? 1 : 0;
            gather_hop_kernel<<<nodeBlocks, BLK, 0, stream>>>(cur, rp, col, norm, s,
                                                              out, nxt, N, write_next);
            __half* t = cur; cur = nxt; nxt = t;
        }
    }
}

// Round 7
// 435.006 us; speedup vs baseline: 9.8829x; 9.8829x over previous
//
#include <hip/hip_runtime.h>
#include <hip/hip_bf16.h>
#include <hip/hip_fp16.h>
#include <math.h>

// DAGNN propagation, CSR-gather, fp16 state.
// Round 20: r19 retry — restore round-14 G8 configuration (best: 442us) with
// non-temporal wnext stores. Fix vs r19: __builtin_nontemporal_store requires
// a NATIVE clang vector type, not HIP_vector_type<float,4>; use
// ext_vector_type(4) float.

#define DIM 64
#define BSH 9
#define BSZ 512                 // nodes per bucket
#define MAXNB 256               // buckets must fit one 256-thread scan block
#define A2_CHUNK 4096           // edges per A2 block

typedef float nfloat4 __attribute__((ext_vector_type(4)));

// ---- zero int region ----
__global__ void zero_int_kernel(int* __restrict__ p, int n) {
    int i = blockIdx.x * blockDim.x + threadIdx.x;
    if (i < n) p[i] = 0;
}

// ---- A1: bucket histogram via LDS bins ----
__global__ void bin_count_kernel(const int* __restrict__ dst,
                                 int* __restrict__ binCount, int E) {
    __shared__ int lb[MAXNB];
    if (threadIdx.x < MAXNB) lb[threadIdx.x] = 0;
    __syncthreads();
    for (int e = blockIdx.x * blockDim.x + threadIdx.x; e < E;
         e += gridDim.x * blockDim.x) {
        atomicAdd(&lb[dst[e] >> BSH], 1);
    }
    __syncthreads();
    if (threadIdx.x < MAXNB && lb[threadIdx.x])
        atomicAdd(&binCount[threadIdx.x], lb[threadIdx.x]);
}

// ---- S: exclusive scan of bucket counts; init tails; rp[N]=E ----
__global__ void binscan_kernel(const int* __restrict__ binCount,
                               int* __restrict__ binBase, int* __restrict__ tail,
                               int* __restrict__ rp, int NB, int N, int E) {
    __shared__ int lds[256];
    int t = threadIdx.x;
    int v = (t < NB) ? binCount[t] : 0;
    lds[t] = v;
    __syncthreads();
    for (int off = 1; off < 256; off <<= 1) {
        int x = (t >= off) ? lds[t - off] : 0;
        __syncthreads();
        lds[t] += x;
        __syncthreads();
    }
    int excl = lds[t] - v;
    if (t < NB) { binBase[t] = excl; tail[t] = excl; }
    if (t == 0) { binBase[NB] = E; rp[N] = E; }
}

// ---- A2: LDS-binned scatter of (src,dst) pairs into bucket regions ----
__global__ void bin_scatter_kernel(const int* __restrict__ src,
                                   const int* __restrict__ dst,
                                   int* __restrict__ tail,
                                   int2* __restrict__ pairs, int E) {
    __shared__ int cnt[MAXNB];
    __shared__ int base[MAXNB];
    int t = threadIdx.x;
    int begE = blockIdx.x * A2_CHUNK;
    int endE = begE + A2_CHUNK; if (endE > E) endE = E;
    if (t < MAXNB) cnt[t] = 0;
    __syncthreads();
    for (int e = begE + t; e < endE; e += blockDim.x)
        atomicAdd(&cnt[dst[e] >> BSH], 1);
    __syncthreads();
    if (t < MAXNB) {
        int c = cnt[t];
        base[t] = c ? atomicAdd(&tail[t], c) : 0;   // one global atomic / bucket / block
        cnt[t] = 0;                                  // reuse as local cursor
    }
    __syncthreads();
    for (int e = begE + t; e < endE; e += blockDim.x) {
        int d = dst[e];
        int b = d >> BSH;
        int pos = base[b] + atomicAdd(&cnt[b], 1);
        pairs[pos] = make_int2(src[e], d);           // coalesced-ish: ~168B windows
    }
}

// ---- B: per-bucket CSR finalize: degree -> scan -> rp/norm/col ----
__global__ void bucket_build_kernel(const int2* __restrict__ pairs,
                                    const int* __restrict__ binBase,
                                    int* __restrict__ col, int* __restrict__ rp,
                                    float* __restrict__ norm, int N) {
    __shared__ int degL[BSZ];
    __shared__ int off[BSZ];
    __shared__ int tmp[256];
    int b  = blockIdx.x;
    int lo = b << BSH;
    int cnt = N - lo; if (cnt > BSZ) cnt = BSZ;
    int t = threadIdx.x;
    degL[t] = 0; degL[t + 256] = 0;
    __syncthreads();
    int rbeg = binBase[b], rend = binBase[b + 1];
    for (int j = rbeg + t; j < rend; j += 256)
        atomicAdd(&degL[pairs[j].y - lo], 1);
    __syncthreads();
    int d0 = degL[2 * t], d1 = degL[2 * t + 1];
    int s2 = d0 + d1;
    tmp[t] = s2;
    __syncthreads();
    for (int o = 1; o < 256; o <<= 1) {
        int x = (t >= o) ? tmp[t - o] : 0;
        __syncthreads();
        tmp[t] += x;
        __syncthreads();
    }
    int e2 = tmp[t] - s2;                  // local exclusive offset
    off[2 * t]     = e2;
    off[2 * t + 1] = e2 + d0;
    __syncthreads();
    if (2 * t < cnt) {
        rp[lo + 2 * t] = rbeg + e2;
        norm[lo + 2 * t] = rsqrtf((float)d0);
    }
    if (2 * t + 1 < cnt) {
        rp[lo + 2 * t + 1] = rbeg + e2 + d0;
        norm[lo + 2 * t + 1] = rsqrtf((float)d1);
    }
    for (int j = rbeg + t; j < rend; j += 256) {
        int2 p = pairs[j];
        int slot = atomicAdd(&off[p.y - lo], 1);     // local cursor
        col[rbeg + slot] = p.x;                      // L2-hot 27KB window
    }
}

// ---- init (full path): w0 = half(feats*norm), node-major 128B rows ----
__global__ void init_w0_kernel(const float* __restrict__ feats,
                               const float* __restrict__ norm,
                               __half* __restrict__ w, int N) {
    int n = blockIdx.x * (blockDim.x >> 6) + (threadIdx.x >> 6);
    int lane = threadIdx.x & 63;
    if (n >= N) return;
    size_t idx = ((size_t)n << 6) + lane;
    w[idx] = __float2half(feats[idx] * norm[n]);
}

// ---- hop (G8, r14): 8 lanes/node, 8 nodes/wave, no cross-lane reduction ----
__global__ void gather_hop_store_kernel(const __half* __restrict__ w,
                                        const int* __restrict__ rp,
                                        const int* __restrict__ col,
                                        const float* __restrict__ norm,
                                        __half* __restrict__ wnext, int N) {
    int wid  = (blockIdx.x * blockDim.x + threadIdx.x) >> 6;   // wave id
    int lane = threadIdx.x & 63;
    int g    = lane >> 3;          // group (node) within wave
    int sub  = lane & 7;           // 8-elem chunk within row
    int gbase = lane & 56;         // first lane of my group
    int n    = (wid << 3) + g;
    bool valid = (n < N);
    int nc = valid ? n : (N - 1);

    int beg = rp[nc];
    int end = rp[nc + 1];
    int deg = valid ? (end - beg) : 0;
    float nm = norm[nc];

    // wave-uniform max degree (deg already uniform within each 8-lane group)
    int maxdeg = deg;
    maxdeg = max(maxdeg, __shfl_xor(maxdeg, 8, 64));
    maxdeg = max(maxdeg, __shfl_xor(maxdeg, 16, 64));
    maxdeg = max(maxdeg, __shfl_xor(maxdeg, 32, 64));

    float acc[8];
    #pragma unroll
    for (int i = 0; i < 8; ++i) acc[i] = 0.0f;

    const __half* wsub = w + (sub << 3);

    for (int base = 0; base < maxdeg; base += 8) {
        // preload this group's next 8 cols: lane 'sub' holds col[beg+base+sub]
        int i0 = beg + base + sub;
        int c0 = (i0 < end) ? col[i0] : 0;
        #pragma unroll
        for (int jj = 0; jj < 8; jj += 2) {
            if (base + jj >= maxdeg) break;          // wave-uniform break
            int ccA = __shfl(c0, gbase + jj, 64);
            int ccB = __shfl(c0, gbase + jj + 1, 64);
            float4 rA = *(const float4*)(wsub + ((size_t)ccA << 6));
            float4 rB = *(const float4*)(wsub + ((size_t)ccB << 6));
            if (base + jj < deg) {
                const __half2* h2 = (const __half2*)&rA;
                float2 f0 = __half22float2(h2[0]);
                float2 f1 = __half22float2(h2[1]);
                float2 f2 = __half22float2(h2[2]);
                float2 f3 = __half22float2(h2[3]);
                acc[0] += f0.x; acc[1] += f0.y;
                acc[2] += f1.x; acc[3] += f1.y;
                acc[4] += f2.x; acc[5] += f2.y;
                acc[6] += f3.x; acc[7] += f3.y;
            }
            if (base + jj + 1 < deg) {
                const __half2* h2 = (const __half2*)&rB;
                float2 f0 = __half22float2(h2[0]);
                float2 f1 = __half22float2(h2[1]);
                float2 f2 = __half22float2(h2[2]);
                float2 f3 = __half22float2(h2[3]);
                acc[0] += f0.x; acc[1] += f0.y;
                acc[2] += f1.x; acc[3] += f1.y;
                acc[4] += f2.x; acc[5] += f2.y;
                acc[6] += f3.x; acc[7] += f3.y;
            }
        }
    }

    if (valid) {
        float n2 = nm * nm;
        __half2 hv[4];
        hv[0] = __floats2half2_rn(acc[0] * n2, acc[1] * n2);
        hv[1] = __floats2half2_rn(acc[2] * n2, acc[3] * n2);
        hv[2] = __floats2half2_rn(acc[4] * n2, acc[5] * n2);
        hv[3] = __floats2half2_rn(acc[6] * n2, acc[7] * n2);
        // wave stores 8 consecutive rows -> contiguous 1KB; non-temporal to
        // avoid evicting the gather-hot set (next hop reads via L3 anyway).
        nfloat4 val = *(const nfloat4*)hv;
        __builtin_nontemporal_store(val,
            (nfloat4*)(wnext + ((size_t)n << 6) + (sub << 3)));
    }
}

// ---- readout (G8): 8 lanes/node; only a 3-op intra-group dot reduce ----
__global__ void readout_kernel(const __half* __restrict__ wbase,
                               const float* __restrict__ norm,
                               const float* __restrict__ s,
                               float* __restrict__ out,
                               int N, int nk, size_t kstride) {
    int wid  = (blockIdx.x * blockDim.x + threadIdx.x) >> 6;
    int lane = threadIdx.x & 63;
    int g    = lane >> 3;
    int sub  = lane & 7;
    int n    = (wid << 3) + g;
    bool valid = (n < N);
    int nc = valid ? n : (N - 1);

    float4 sa = *(const float4*)(s + (sub << 3));
    float4 sb = *(const float4*)(s + (sub << 3) + 4);

    float inm = 1.0f / norm[nc];
    size_t rowoff = ((size_t)nc << 6) + (sub << 3);

    float acc[8];
    #pragma unroll
    for (int i = 0; i < 8; ++i) acc[i] = 0.0f;

    for (int k = 0; k < nk; ++k) {
        float4 raw = *(const float4*)(wbase + rowoff + (size_t)k * kstride);
        const __half2* h2 = (const __half2*)&raw;
        float2 f0 = __half22float2(h2[0]);
        float2 f1 = __half22float2(h2[1]);
        float2 f2 = __half22float2(h2[2]);
        float2 f3 = __half22float2(h2[3]);
        // dot(w_k_row, s) in raw (pre-scaled) space, then scale by inm
        float p = f0.x * sa.x + f0.y * sa.y + f1.x * sa.z + f1.y * sa.w
                + f2.x * sb.x + f2.y * sb.y + f3.x * sb.z + f3.y * sb.w;
        p += __shfl_xor(p, 1, 64);
        p += __shfl_xor(p, 2, 64);
        p += __shfl_xor(p, 4, 64);
        float gate = 1.0f / (1.0f + expf(-p * inm));
        float g2 = gate * inm;                       // fold h = w*inm into gate
        acc[0] += g2 * f0.x; acc[1] += g2 * f0.y;
        acc[2] += g2 * f1.x; acc[3] += g2 * f1.y;
        acc[4] += g2 * f2.x; acc[5] += g2 * f2.y;
        acc[6] += g2 * f3.x; acc[7] += g2 * f3.y;
    }

    if (valid) {
        float4 o0 = make_float4(acc[0], acc[1], acc[2], acc[3]);
        float4 o1 = make_float4(acc[4], acc[5], acc[6], acc[7]);
        float4* o = (float4*)(out + rowoff);
        o[0] = o0; o[1] = o1;
    }
}

// ---- fallback (small ws): fused hop with out RMW ----
__global__ void init_kernel(const float* __restrict__ feats,
                            const float* __restrict__ norm,
                            const float* __restrict__ s,
                            float* __restrict__ out,
                            __half* __restrict__ w, int N) {
    int n = blockIdx.x * (blockDim.x >> 6) + (threadIdx.x >> 6);
    int lane = threadIdx.x & 63;
    if (n >= N) return;
    size_t idx = ((size_t)n << 6) + lane;
    float v = feats[idx];
    float p = v * s[lane];
    #pragma unroll
    for (int off = 32; off; off >>= 1) p += __shfl_xor(p, off, 64);
    float gate = 1.0f / (1.0f + expf(-p));
    out[idx] = gate * v;
    w[idx] = __float2half(v * norm[n]);
}

__global__ void gather_hop_kernel(const __half* __restrict__ w,
                                  const int* __restrict__ rp,
                                  const int* __restrict__ col,
                                  const float* __restrict__ norm,
                                  const float* __restrict__ s,
                                  float* __restrict__ out,
                                  __half* __restrict__ wnext,
                                  int N, int write_next) {
    int n = blockIdx.x * (blockDim.x >> 6) + (threadIdx.x >> 6);
    if (n >= N) return;
    int lane = threadIdx.x & 63;
    int e_sub = lane >> 3;
    int c     = lane & 7;

    int beg = rp[n];
    int end = rp[n + 1];

    float acc[8];
    #pragma unroll
    for (int i = 0; i < 8; ++i) acc[i] = 0.0f;

    for (int j = beg + e_sub; j < end; j += 8) {
        int cc = col[j];
        float4 raw = *(const float4*)(w + ((size_t)cc << 6) + (c << 3));
        const __half2* h2 = (const __half2*)&raw;
        float2 f0 = __half22float2(h2[0]);
        float2 f1 = __half22float2(h2[1]);
        float2 f2 = __half22float2(h2[2]);
        float2 f3 = __half22float2(h2[3]);
        acc[0] += f0.x; acc[1] += f0.y;
        acc[2] += f1.x; acc[3] += f1.y;
        acc[4] += f2.x; acc[5] += f2.y;
        acc[6] += f3.x; acc[7] += f3.y;
    }

    #pragma unroll
    for (int off = 8; off < 64; off <<= 1) {
        #pragma unroll
        for (int i = 0; i < 8; ++i) acc[i] += __shfl_xor(acc[i], off, 64);
    }

    float nm = norm[n];
    float v[8];
    #pragma unroll
    for (int i = 0; i < 8; ++i) v[i] = acc[i] * nm;

    float4 sa = *(const float4*)(s + (c << 3));
    float4 sb = *(const float4*)(s + (c << 3) + 4);
    float p = v[0] * sa.x + v[1] * sa.y + v[2] * sa.z + v[3] * sa.w
            + v[4] * sb.x + v[5] * sb.y + v[6] * sb.z + v[7] * sb.w;
    #pragma unroll
    for (int off = 1; off < 8; off <<= 1) p += __shfl_xor(p, off, 64);
    float gate = 1.0f / (1.0f + expf(-p));

    size_t base = ((size_t)n << 6) + (c << 3);
    if (e_sub == 0) {
        float4* o = (float4*)(out + base);
        float4 o0 = o[0], o1 = o[1];
        o0.x += gate * v[0]; o0.y += gate * v[1];
        o0.z += gate * v[2]; o0.w += gate * v[3];
        o1.x += gate * v[4]; o1.y += gate * v[5];
        o1.z += gate * v[6]; o1.w += gate * v[7];
        o[0] = o0; o[1] = o1;
    } else if (e_sub == 1 && write_next) {
        __half2 hv[4];
        hv[0] = __floats2half2_rn(v[0] * nm, v[1] * nm);
        hv[1] = __floats2half2_rn(v[2] * nm, v[3] * nm);
        hv[2] = __floats2half2_rn(v[4] * nm, v[5] * nm);
        hv[3] = __floats2half2_rn(v[6] * nm, v[7] * nm);
        *(float4*)(wnext + base) = *(const float4*)hv;
    }
}

extern "C" void kernel_launch(void* const* d_in, const int* in_sizes, int n_in,
                              void* d_out, int out_size, void* d_ws, size_t ws_size,
                              hipStream_t stream) {
    const float* feats = (const float*)d_in[0];
    const float* s     = (const float*)d_in[1];
    const int*   src   = (const int*)d_in[2];
    const int*   dst   = (const int*)d_in[3];
    float* out = (float*)d_out;

    const int N = in_sizes[0] / DIM;
    const int E = in_sizes[2];
    const int K = 10;
    const int NB = (N + BSZ - 1) >> BSH;    // 196 for N=100000; must be <= 256

    const int BLK = 256;
    const int wavesPerBlk = BLK / 64;
    int nodeBlocks  = (N + wavesPerBlk - 1) / wavesPerBlk;           // 1 node/wave
    int nodeBlocks8 = (N + wavesPerBlk * 8 - 1) / (wavesPerBlk * 8); // 8 nodes/wave
    int a2Blocks = (E + A2_CHUNK - 1) / A2_CHUNK;

    size_t stateElems = (size_t)N * DIM;
    // ws layout: norm(N f) | wbase(nbuf*stateElems h) | rp(N+1) | col(E)
    //            | binCount(256) | binBase(257) | tail(256) | pad | pairs(E int2)
    size_t intCount = (size_t)(N + 1) + E + 256 + 257 + 256;
    size_t need_full = (size_t)N * 4 + (size_t)(K + 1) * stateElems * 2
                     + intCount * 4 + (size_t)E * 8 + 64;
    int full = (ws_size >= need_full) ? 1 : 0;
    int nbuf = full ? (K + 1) : 2;

    float*  norm    = (float*)d_ws;
    __half* wbase   = (__half*)(norm + N);
    int*    rp      = (int*)(wbase + (size_t)nbuf * stateElems);
    int*    col     = rp + (N + 1);
    int*    binCount= col + E;
    int*    binBase = binCount + 256;
    int*    tail    = binBase + 257;
    size_t  poff    = (size_t)((char*)(tail + 256) - (char*)d_ws);
    poff = (poff + 7) & ~(size_t)7;
    int2*   pairs   = (int2*)((char*)d_ws + poff);

    // ---- build: histogram -> scan -> binned scatter -> bucket finalize ----
    zero_int_kernel<<<1, 256, 0, stream>>>(binCount, 256);
    bin_count_kernel<<<512, BLK, 0, stream>>>(dst, binCount, E);
    binscan_kernel<<<1, 256, 0, stream>>>(binCount, binBase, tail, rp, NB, N, E);
    bin_scatter_kernel<<<a2Blocks, BLK, 0, stream>>>(src, dst, tail, pairs, E);
    bucket_build_kernel<<<NB, 256, 0, stream>>>(pairs, binBase, col, rp, norm, N);

    if (full) {
        init_w0_kernel<<<nodeBlocks, BLK, 0, stream>>>(feats, norm, wbase, N);
        for (int k = 0; k < K; ++k) {
            const __half* cur = wbase + (size_t)k * stateElems;
            __half* nxt = wbase + (size_t)(k + 1) * stateElems;
            gather_hop_store_kernel<<<nodeBlocks8, BLK, 0, stream>>>(cur, rp, col,
                                                                     norm, nxt, N);
        }
        readout_kernel<<<nodeBlocks8, BLK, 0, stream>>>(wbase, norm, s, out,
                                                        N, K + 1, stateElems);
    } else {
        __half* wA = wbase;
        __half* wB = wbase + stateElems;
        init_kernel<<<nodeBlocks, BLK, 0, stream>>>(feats, norm, s, out, wA, N);
        __half* cur = wA;
        __half* nxt = wB;
        for (int k = 0; k < K; ++k) {
            int write_next = (k < K - 1) ? 1 : 0;
            gather_hop_kernel<<<nodeBlocks, BLK, 0, stream>>>(cur, rp, col, norm, s,
                                                              out, nxt, N, write_next);
            __half* t = cur; cur = nxt; nxt = t;
        }
    }
}